// Round 12
// baseline (290.073 us; speedup 1.0000x reference)
//
#include <hip/hip_runtime.h>
#include <hip/hip_bf16.h>

// B=2, S=2048, D=1024, H=16, HD=64, RANK=8, ALPHA=8. ALL I/O FP32.
// R24 = R23 with ONE attn change: triple-buffered K/V + counted vmcnt.
//  - 3 K/V buffers (78,080 B LDS, still 2 blocks/CU), prefetch distance 2
//  - per-chunk sync = s_waitcnt vmcnt(6) + raw s_barrier + sched_barrier(0)
//    (was __syncthreads whose implicit vmcnt(0) drained the JUST-issued
//    next-chunk loads -> exposed latency every chunk). vmcnt(0) only on the
//    last chunk; __syncthreads between q-tiles.
//  - invariant: at iter c outstanding = chunks {c, c+1} (6 loads each, FIFO)
//    -> vmcnt(6) == chunk c landed. buf[(c+2)%3] == buf[(c-1)%3], whose
//    reads completed before each wave passed this iter's barrier.
// prep_all/gemm3 byte-identical to R23/R21.
// ws (72 MB): qf 0-16 | khi 16-24 | klo 24-32 | vt 32-40 |
//             wpt hi 40-42 lo 42-44 | wqt hi 44-50 lo 50-56 |
//             xhi 56-64 xlo 64-72 | ctxhi 44-52 ctxlo 52-60 (overlay dead).

#define BB    2
#define SS    2048
#define DD    1024
#define HH    16
#define HDIM  64
#define N3    3072
#define MR    4096

typedef short short8 __attribute__((ext_vector_type(8)));
typedef short s16x4 __attribute__((ext_vector_type(4)));
typedef float f32x4 __attribute__((ext_vector_type(4)));

#define MFMA16(a, b, c) __builtin_amdgcn_mfma_f32_16x16x32_bf16((a), (b), (c), 0, 0, 0)

__device__ __forceinline__ float b2f(short s) {
    union { unsigned int u; float f; } c;
    c.u = ((unsigned int)(unsigned short)s) << 16;
    return c.f;
}
__device__ __forceinline__ short f2b(float f) {
    union { __hip_bfloat16 h; short s; } c;
    c.h = __float2bfloat16(f);
    return c.s;
}
struct HiLo { short hi, lo; };
__device__ __forceinline__ HiLo split2(float v) {
    HiLo r;
    r.hi = f2b(v);
    r.lo = f2b(v - b2f(r.hi));   // exact residual; next 8 mantissa bits
    return r;
}

__device__ __forceinline__ void gl_lds16(const void* g, void* l) {
    __builtin_amdgcn_global_load_lds(
        (const __attribute__((address_space(1))) void*)g,
        (__attribute__((address_space(3))) void*)l, 16, 0, 0);
}

// Tile-major offset for bf16 operand matrices consumed by gemm3:
// X[m][k] lives at ((m>>7)*32 + (k>>5))*4096 + ((k>>3)&3)*1024 + (m&127)*8 + (k&7)

// ---------------------------------------------------------------- prep_all
// One kernel, 2048 blocks x 256 thr:
//   bid <  768 : prep(Wq + LoRA) -> wqt hi/lo tile-major
//   bid < 1024 : prep(Wp)        -> wpt hi/lo tile-major
//   bid >=1024 : split_x         -> xhi/xlo tile-major
__global__ __launch_bounds__(256) void prep_all(
    const float* __restrict__ X, short* __restrict__ Xhi, short* __restrict__ Xlo,
    const float* __restrict__ Wq, const float* __restrict__ Al,
    const float* __restrict__ Bl, short* __restrict__ Wqhi, short* __restrict__ Wqlo,
    const float* __restrict__ Wp, short* __restrict__ Wphi, short* __restrict__ Wplo)
{
    __shared__ float sw[64][68];
    __shared__ float sa[64][8];
    __shared__ float sb[8][64];
    int bid = blockIdx.x;
    int tid = threadIdx.x;

    if (bid >= 1024) {                     // ---- split_x body
        int id = bid - 1024;
        int kc = id & 31, p = id >> 5;
        int row = tid >> 1, half = tid & 1;
        const float* src = &X[((size_t)p * 128 + row) * 1024 + kc * 32 + half * 16];
        f32x4 v[4];
#pragma unroll
        for (int u = 0; u < 4; u++) v[u] = *(const f32x4*)(src + u * 4);
        size_t base = ((size_t)p * 32 + kc) * 4096 + (size_t)(half * 2) * 1024 + row * 8;
#pragma unroll
        for (int u = 0; u < 2; u++) {
            short8 h8, l8;
#pragma unroll
            for (int j = 0; j < 8; j++) {
                HiLo hl = split2(v[u * 2 + (j >> 2)][j & 3]);
                h8[j] = hl.hi; l8[j] = hl.lo;
            }
            *(short8*)&Xhi[base + u * 1024] = h8;
            *(short8*)&Xlo[base + u * 1024] = l8;
        }
        return;
    }

    // ---- prep body (Wq with LoRA, or Wp without)
    const float* W; short *Whi, *Wlo;
    int N, lora, bx, by;
    if (bid < 768) {
        W = Wq; Whi = Wqhi; Wlo = Wqlo; N = N3; lora = 1;
        bx = bid % 48; by = bid / 48;
    } else {
        int id = bid - 768;
        W = Wp; Whi = Wphi; Wlo = Wplo; N = DD; lora = 0;
        bx = id & 15; by = id >> 4;
    }
    int n0 = bx * 64, k0 = by * 64;
#pragma unroll
    for (int p = 0; p < 4; p++) {
        int idx = p * 256 + tid;
        int kr = idx >> 4, ch = idx & 15;
        *(f32x4*)&sw[kr][ch * 4] = *(const f32x4*)&W[(size_t)(k0 + kr) * N + n0 + ch * 4];
    }
    if (lora) {
        if (tid < 64) {
#pragma unroll
            for (int r = 0; r < 8; r++) sa[tid][r] = Al[(k0 + tid) * 8 + r];
        } else if (tid < 128) {
            int c = tid - 64;
#pragma unroll
            for (int r = 0; r < 8; r++) sb[r][c] = Bl[(size_t)r * N + n0 + c];
        }
    }
    __syncthreads();
#pragma unroll
    for (int p = 0; p < 2; p++) {
        int idx = p * 256 + tid;
        int nr = idx >> 3, ch = idx & 7;
        short8 h8, l8;
#pragma unroll
        for (int j = 0; j < 8; j++) {
            int k = ch * 8 + j;
            float v = sw[k][nr];
            if (lora) {
                float a2 = 0.f;
#pragma unroll
                for (int r = 0; r < 8; r++) a2 += sa[k][r] * sb[r][nr];
                v += 8.0f * a2;
            }
            HiLo hl = split2(v);
            h8[j] = hl.hi;
            l8[j] = hl.lo;
        }
        int n = n0 + nr;
        int kchunk = (k0 >> 5) + (ch >> 2);
        size_t off = ((size_t)(n >> 7) * 32 + kchunk) * 4096 +
                     (size_t)(ch & 3) * 1024 + (n & 127) * 8;
        *(short8*)&Whi[off] = h8;
        *(short8*)&Wlo[off] = l8;
    }
}

// ---------------------------------------------------------------- gemm3
// C[m][n] = sum_k (Ahi+Alo)[m][k]*(Bhi+Blo)[n][k] (3-term hi/lo) + bias[n].
// Double-buffered LDS; K-step t+1's 8 gl_lds16 issued before t's compute;
// one barrier per K-step. mode 0 (QKV): n<1024 -> qf = v*0.125 (fp32);
// 1024..2047 -> khi/klo bf16 split, attn-LDS layout (key-slot XOR-swizzled);
// >=2048 -> vt bf16, attn-LDS layout (hd-slot XOR-swizzled).
// mode 1 (proj): outf32 row-major.
__global__ __launch_bounds__(256) void gemm3(
    const short* __restrict__ Ahi, const short* __restrict__ Alo,
    const short* __restrict__ Bhi, const short* __restrict__ Blo,
    const float* __restrict__ bias,
    float* __restrict__ qf, short* __restrict__ khi, short* __restrict__ klo,
    short* __restrict__ vt, float* __restrict__ outf32, int N, int mode)
{
    __shared__ short lds[2][4][4][128][8];  // [dbuf][mat(Ah,Al,Bh,Bl)][q4][row][j]
    int tid = threadIdx.x;
    int wav = tid >> 6, lane = tid & 63;
    int l15 = lane & 15, q4 = lane >> 4;
    int wm = wav & 1, wn = wav >> 1;
    int n0 = blockIdx.x * 128, m0 = blockIdx.y * 128;

    const short* ga_h = Ahi + ((size_t)blockIdx.y * 32) * 4096 + tid * 8;
    const short* ga_l = Alo + ((size_t)blockIdx.y * 32) * 4096 + tid * 8;
    const short* gb_h = Bhi + ((size_t)blockIdx.x * 32) * 4096 + tid * 8;
    const short* gb_l = Blo + ((size_t)blockIdx.x * 32) * 4096 + tid * 8;
    short* l0 = &lds[0][0][0][0][0] + tid * 8;

    f32x4 acc[4][4] = {};

#define STAGE(kc_, buf_)                                         \
    {                                                            \
        int koff_ = (kc_) * 4096;                                \
        short* lb_ = l0 + (buf_) * 16384;                        \
        gl_lds16(ga_h + koff_,        lb_);                      \
        gl_lds16(ga_h + koff_ + 2048, lb_ + 2048);               \
        gl_lds16(ga_l + koff_,        lb_ + 4096);               \
        gl_lds16(ga_l + koff_ + 2048, lb_ + 6144);               \
        gl_lds16(gb_h + koff_,        lb_ + 8192);               \
        gl_lds16(gb_h + koff_ + 2048, lb_ + 10240);              \
        gl_lds16(gb_l + koff_,        lb_ + 12288);              \
        gl_lds16(gb_l + koff_ + 2048, lb_ + 14336);              \
    }

    STAGE(0, 0);
    __syncthreads();               // implicit vmcnt(0): K-step 0 staged

    for (int kc = 0; kc < 32; ++kc) {
        int cur = kc & 1;
        if (kc + 1 < 32) STAGE(kc + 1, cur ^ 1);   // travels under compute
        short8 ah[4], al_[4], bh[4], bl[4];
#pragma unroll
        for (int i = 0; i < 4; i++) {
            ah[i]  = *(short8*)&lds[cur][0][q4][wm * 64 + i * 16 + l15][0];
            al_[i] = *(short8*)&lds[cur][1][q4][wm * 64 + i * 16 + l15][0];
            bh[i]  = *(short8*)&lds[cur][2][q4][wn * 64 + i * 16 + l15][0];
            bl[i]  = *(short8*)&lds[cur][3][q4][wn * 64 + i * 16 + l15][0];
        }
#pragma unroll
        for (int mi = 0; mi < 4; mi++)
#pragma unroll
            for (int ni = 0; ni < 4; ni++) {
                acc[mi][ni] = MFMA16(ah[mi], bh[ni], acc[mi][ni]);
                acc[mi][ni] = MFMA16(ah[mi], bl[ni], acc[mi][ni]);
                acc[mi][ni] = MFMA16(al_[mi], bh[ni], acc[mi][ni]);
            }
        __syncthreads();           // drains K+1 loads (issued pre-compute) +
                                   // all waves done reading lds[cur]
    }
#undef STAGE
#pragma unroll
    for (int ni = 0; ni < 4; ni++) {
        int n = n0 + wn * 64 + ni * 16 + l15;
        float bv = bias[n];
#pragma unroll
        for (int mi = 0; mi < 4; mi++) {
            int mbase = m0 + wm * 64 + mi * 16 + q4 * 4;
#pragma unroll
            for (int r = 0; r < 4; r++) {
                int m = mbase + r;
                float v = acc[mi][ni][r] + bv;
                if (mode != 0) {
                    outf32[(size_t)m * 1024 + n] = v;
                } else if (n0 < 1024) {
                    qf[(size_t)m * 1024 + n] = v * 0.125f;   // pow2: exact
                } else if (n0 < 2048) {
                    int kk = n - 1024, hh = kk >> 6, hd = kk & 63;
                    int bb_ = m >> 11, s = m & 2047;
                    int oct = hd >> 3;
                    size_t base = ((size_t)((bb_ << 4) + hh) * 32 + (s >> 6)) * 4096
                                  + (size_t)oct * 512 + ((s & 63) ^ oct) * 8 + (hd & 7);
                    HiLo hl = split2(v);
                    khi[base] = hl.hi;
                    klo[base] = hl.lo;
                } else {
                    int kk = n - 2048, hh = kk >> 6, hd = kk & 63;
                    int bb_ = m >> 11, s = m & 2047;
                    int oct = (s >> 3) & 7;
                    size_t base = ((size_t)((bb_ << 4) + hh) * 32 + (s >> 6)) * 4096
                                  + (size_t)oct * 512 + (hd ^ oct) * 8 + (s & 7);
                    vt[base] = f2b(v);
                }
            }
        }
    }
}

// ---------------------------------------------------------------- attn_mfma
// grid (16, H, B) = 512 blocks x 256 thr; block x handles q-tiles {31-x, x}.
// TRIPLE-buffered K/V (prefetch distance 2) + counted vmcnt(6) + raw
// s_barrier per chunk (vmcnt(0) only on the last chunk). Swapped QK^T
// (mfma(K,Q)); in-lane softmax + 2 shfl_xor; two-phase Pt (4.3KB).
// LDS 78,080 B -> 2 blocks/CU.
__global__ __launch_bounds__(256) void attn_mfma(const float* __restrict__ qf,
                                                 const short* __restrict__ khi,
                                                 const short* __restrict__ klo,
                                                 const short* __restrict__ vtg,
                                                 short* __restrict__ ctxhi,
                                                 short* __restrict__ ctxlo) {
    __shared__ short KhL[3][4096];      // [buf][oct*512 + (key^oct)*8 + (hd&7)]
    __shared__ short KlL[3][4096];
    __shared__ short VtL[3][4096];      // [buf][oct*512 + (hd^oct)*8 + (key&7)]
    __shared__ short Pt[4][4][17][8];   // [wave][key-octet%4][qrow(+pad)][j]

    int h = blockIdx.y, b = blockIdx.z;
    int tid = threadIdx.x, wav = tid >> 6, lane = tid & 63;
    int l15 = lane & 15, q4 = lane >> 4;
    const float* bq = qf + (size_t)b * SS * 1024;
    size_t hb = (size_t)((b * 16 + h) * 32) * 4096;
    const short* gkh = khi + hb;
    const short* gkl = klo + hb;
    const short* gvt = vtg + hb;
    int t8 = tid * 8;

#define ISSUE(c, buf)                                                   \
    {                                                                   \
        size_t co_ = (size_t)(c) * 4096 + t8;                           \
        gl_lds16(gkh + co_,        &KhL[buf][t8]);                      \
        gl_lds16(gkh + co_ + 2048, &KhL[buf][t8 + 2048]);               \
        gl_lds16(gkl + co_,        &KlL[buf][t8]);                      \
        gl_lds16(gkl + co_ + 2048, &KlL[buf][t8 + 2048]);               \
        gl_lds16(gvt + co_,        &VtL[buf][t8]);                      \
        gl_lds16(gvt + co_ + 2048, &VtL[buf][t8 + 2048]);               \
    }

    for (int t = 0; t < 2; ++t) {
        int qt = t ? (int)blockIdx.x : 31 - (int)blockIdx.x;
        int qb = qt * 64;

        // Q fragments (values pre-scaled by 0.125 in gemm3 epilogue)
        size_t qoff = (size_t)(qb + wav * 16 + l15) * 1024 + h * 64;
        short8 q0h, q0l, q1h, q1l;
        {
            f32x4 a0 = *(const f32x4*)&bq[qoff + q4 * 8];
            f32x4 a1 = *(const f32x4*)&bq[qoff + q4 * 8 + 4];
            f32x4 c0 = *(const f32x4*)&bq[qoff + 32 + q4 * 8];
            f32x4 c1 = *(const f32x4*)&bq[qoff + 32 + q4 * 8 + 4];
#pragma unroll
            for (int j = 0; j < 4; j++) {
                HiLo u = split2(a0[j]); q0h[j] = u.hi; q0l[j] = u.lo;
                HiLo v = split2(a1[j]); q0h[4 + j] = v.hi; q0l[4 + j] = v.lo;
                HiLo w = split2(c0[j]); q1h[j] = w.hi; q1l[j] = w.lo;
                HiLo z = split2(c1[j]); q1h[4 + j] = z.hi; q1l[4 + j] = z.lo;
            }
        }

        f32x4 o[4] = {};
        float msc = -1e30f;    // running max for q-row l15 (per lane)
        float lsc = 0.f;       // running sum for q-row l15
        int nch = qt + 1;

        ISSUE(0, 0);
        if (nch > 1) ISSUE(1, 1);

        for (int c = 0; c < nch; ++c) {
            int cur = c % 3;
            int k0 = c * 64;

            // counted wait: chunks {c, c+1} outstanding (6 loads each, FIFO)
            if (c + 1 < nch) {
                asm volatile("s_waitcnt vmcnt(6)" ::: "memory");
            } else {
                asm volatile("s_waitcnt vmcnt(0)" ::: "memory");
            }
            __builtin_amdgcn_s_barrier();        // buf[(c+2)%3]==buf[(c-1)%3]
            __builtin_amdgcn_sched_barrier(0);   // pin ds_reads below (rule 18)

            if (c + 2 < nch) ISSUE(c + 2, (c + 2) % 3);

            // ---- scores^T via mfma(K, Q): row = key (q4*4+r), col = qrow (l15)
            f32x4 s[4];
            __builtin_amdgcn_s_setprio(1);
#pragma unroll
            for (int g = 0; g < 4; g++) {
                int ko  = q4 * 512 + ((g * 16 + l15) ^ q4) * 8;
                int ko2 = (4 + q4) * 512 + ((g * 16 + l15) ^ (4 + q4)) * 8;
                short8 k0h_ = *(short8*)&KhL[cur][ko];
                short8 k0l_ = *(short8*)&KlL[cur][ko];
                short8 k1h_ = *(short8*)&KhL[cur][ko2];
                short8 k1l_ = *(short8*)&KlL[cur][ko2];
                f32x4 acc = {};
                acc = MFMA16(k0h_, q0h, acc);
                acc = MFMA16(k0l_, q0h, acc);
                acc = MFMA16(k0h_, q0l, acc);
                acc = MFMA16(k1h_, q1h, acc);
                acc = MFMA16(k1l_, q1h, acc);
                acc = MFMA16(k1h_, q1l, acc);
                s[g] = acc;
            }
            __builtin_amdgcn_s_setprio(0);

            // ---- online softmax: lane owns q-row l15; keys g*16+q4*4+r in regs
            if (c == qt) {            // diagonal chunk: causal mask
                int q = qb + wav * 16 + l15;
#pragma unroll
                for (int g = 0; g < 4; g++)
#pragma unroll
                    for (int r = 0; r < 4; r++)
                        if (k0 + g * 16 + q4 * 4 + r > q) s[g][r] = -1e30f;
            }
            f32x4 mx4 = s[0];
#pragma unroll
            for (int g = 1; g < 4; g++) {
                mx4[0] = fmaxf(mx4[0], s[g][0]); mx4[1] = fmaxf(mx4[1], s[g][1]);
                mx4[2] = fmaxf(mx4[2], s[g][2]); mx4[3] = fmaxf(mx4[3], s[g][3]);
            }
            float mx = fmaxf(fmaxf(mx4[0], mx4[1]), fmaxf(mx4[2], mx4[3]));
            mx = fmaxf(mx, __shfl_xor(mx, 16, 64));
            mx = fmaxf(mx, __shfl_xor(mx, 32, 64));
            float mn = fmaxf(msc, mx);
            f32x4 ps = {};
            s16x4 pb[4];
#pragma unroll
            for (int g = 0; g < 4; g++) {
#pragma unroll
                for (int r = 0; r < 4; r++) {
                    float p = __expf(s[g][r] - mn);
                    ps[r] += p;
                    pb[g][r] = f2b(p);
                }
            }
            float sm = (ps[0] + ps[1]) + (ps[2] + ps[3]);
            sm += __shfl_xor(sm, 16, 64);
            sm += __shfl_xor(sm, 32, 64);
            float alpha_s = __expf(msc - mn);
            msc = mn;
            lsc = lsc * alpha_s + sm;
            float al0 = __shfl(alpha_s, q4 * 4 + 0, 64);
            float al1 = __shfl(alpha_s, q4 * 4 + 1, 64);
            float al2 = __shfl(alpha_s, q4 * 4 + 2, 64);
            float al3 = __shfl(alpha_s, q4 * 4 + 3, 64);

            // ---- PV phase A: keys 0..31 (octets 0-3 of this chunk)
            *(s16x4*)&Pt[wav][0 + (q4 >> 1)][l15][(q4 & 1) * 4] = pb[0];
            *(s16x4*)&Pt[wav][2 + (q4 >> 1)][l15][(q4 & 1) * 4] = pb[1];
            short8 pf0 = *(short8*)&Pt[wav][q4][l15][0];
            __builtin_amdgcn_s_setprio(1);
#pragma unroll
            for (int gg = 0; gg < 4; gg++) {
                int vo = q4 * 512 + ((gg * 16 + l15) ^ q4) * 8;
                short8 vf0 = *(short8*)&VtL[cur][vo];
                f32x4 tt = o[gg];
                tt[0] *= al0; tt[1] *= al1; tt[2] *= al2; tt[3] *= al3;
                o[gg] = MFMA16(pf0, vf0, tt);
            }
            __builtin_amdgcn_s_setprio(0);

            // ---- PV phase B: keys 32..63 reuse the same Pt slab (same-wave
            // DS ops are in-order -> pf0 already read; no barrier).
            *(s16x4*)&Pt[wav][0 + (q4 >> 1)][l15][(q4 & 1) * 4] = pb[2];
            *(s16x4*)&Pt[wav][2 + (q4 >> 1)][l15][(q4 & 1) * 4] = pb[3];
            short8 pf1 = *(short8*)&Pt[wav][q4][l15][0];
            __builtin_amdgcn_s_setprio(1);
#pragma unroll
            for (int gg = 0; gg < 4; gg++) {
                int vo2 = (4 + q4) * 512 + ((gg * 16 + l15) ^ (4 + q4)) * 8;
                short8 vf1 = *(short8*)&VtL[cur][vo2];
                o[gg] = MFMA16(pf1, vf1, o[gg]);
            }
            __builtin_amdgcn_s_setprio(0);
            // no barrier here: next iter's top barrier orders buffer reuse
        }

        float ls0 = __shfl(lsc, q4 * 4 + 0, 64);
        float ls1 = __shfl(lsc, q4 * 4 + 1, 64);
        float ls2 = __shfl(lsc, q4 * 4 + 2, 64);
        float ls3 = __shfl(lsc, q4 * 4 + 3, 64);
        float lsr[4] = {ls0, ls1, ls2, ls3};
#pragma unroll
        for (int gg = 0; gg < 4; gg++)
#pragma unroll
            for (int r = 0; r < 4; r++) {
                int q = qb + wav * 16 + q4 * 4 + r;
                int mrow = b * SS + q;
                int k = h * 64 + gg * 16 + l15;
                HiLo hl = split2(o[gg][r] / lsr[r]);
                size_t off = ((size_t)(mrow >> 7) * 32 + (k >> 5)) * 4096 +
                             (size_t)((k >> 3) & 3) * 1024 + (mrow & 127) * 8 + (k & 7);
                ctxhi[off] = hl.hi;
                ctxlo[off] = hl.lo;
            }
        __syncthreads();   // full drain before next tile reuses buffers 0/1
    }
#undef ISSUE
}

extern "C" void kernel_launch(void* const* d_in, const int* in_sizes, int n_in,
                              void* d_out, int out_size, void* d_ws, size_t ws_size,
                              hipStream_t stream) {
    const float* x  = (const float*)d_in[0];
    const float* Wq = (const float*)d_in[1];
    const float* bq = (const float*)d_in[2];
    const float* Al = (const float*)d_in[3];
    const float* Bl = (const float*)d_in[4];
    const float* Wp = (const float*)d_in[5];
    const float* bp = (const float*)d_in[6];

    char* ws = (char*)d_ws;
    float* qf     = (float*)(ws);                             // 0-16 MB
    short* khi    = (short*)(ws + (size_t)16 * 1024 * 1024);  // 16-24
    short* klo    = (short*)(ws + (size_t)24 * 1024 * 1024);  // 24-32
    short* vt     = (short*)(ws + (size_t)32 * 1024 * 1024);  // 32-40
    short* wpt_hi = (short*)(ws + (size_t)40 * 1024 * 1024);  // 40-42
    short* wpt_lo = (short*)(ws + (size_t)42 * 1024 * 1024);  // 42-44
    short* wqt_hi = (short*)(ws + (size_t)44 * 1024 * 1024);  // 44-50
    short* wqt_lo = (short*)(ws + (size_t)50 * 1024 * 1024);  // 50-56
    short* xhi    = (short*)(ws + (size_t)56 * 1024 * 1024);  // 56-64
    short* xlo    = (short*)(ws + (size_t)64 * 1024 * 1024);  // 64-72
    short* ctxhi  = (short*)(ws + (size_t)44 * 1024 * 1024);  // 44-52 (overlays dead wqt_hi)
    short* ctxlo  = (short*)(ws + (size_t)52 * 1024 * 1024);  // 52-60 (overlays dead wqt_lo/xhi)

    hipLaunchKernelGGL(prep_all, dim3(2048), dim3(256), 0, stream,
                       x, xhi, xlo, Wq, Al, Bl, wqt_hi, wqt_lo,
                       Wp, wpt_hi, wpt_lo);
    hipLaunchKernelGGL(gemm3, dim3(N3 / 128, MR / 128), dim3(256), 0, stream,
                       xhi, xlo, wqt_hi, wqt_lo, bq,
                       qf, khi, klo, vt, (float*)nullptr, N3, 0);
    hipLaunchKernelGGL(attn_mfma, dim3(SS / 128, HH, BB), dim3(256), 0, stream,
                       qf, khi, klo, vt, ctxhi, ctxlo);
    hipLaunchKernelGGL(gemm3, dim3(DD / 128, MR / 128), dim3(256), 0, stream,
                       ctxhi, ctxlo, wpt_hi, wpt_lo, bp,
                       (float*)nullptr, (short*)nullptr, (short*)nullptr,
                       (short*)nullptr, (float*)d_out, DD, 1);
}

// Round 13
// 271.602 us; speedup vs baseline: 1.0680x; 1.0680x over previous
//
#include <hip/hip_runtime.h>
#include <hip/hip_bf16.h>

// B=2, S=2048, D=1024, H=16, HD=64, RANK=8, ALPHA=8. ALL I/O FP32.
// R25 = R23 with ONE attn change: the block's two q-tiles {31-x, x} are
// FUSED into one chunk loop (tile x's chunks are a subset of tile 31-x's).
// Staging/barriers per block: 34 -> 32-x (avg 24.5, -28%); compute per
// block unchanged (33 tile-chunks); each barrier covers up to 2x MFMA.
// Per-tile math byte-identical to R23 (dbuf K/V, two-phase Pt, swapped
// QK^T, in-lane softmax). R24's counted-vmcnt REVERTED (neutral).
// prep_all/gemm3 byte-identical to R21.
// ws (72 MB): qf 0-16 | khi 16-24 | klo 24-32 | vt 32-40 |
//             wpt hi 40-42 lo 42-44 | wqt hi 44-50 lo 50-56 |
//             xhi 56-64 xlo 64-72 | ctxhi 44-52 ctxlo 52-60 (overlay dead).

#define BB    2
#define SS    2048
#define DD    1024
#define HH    16
#define HDIM  64
#define N3    3072
#define MR    4096

typedef short short8 __attribute__((ext_vector_type(8)));
typedef short s16x4 __attribute__((ext_vector_type(4)));
typedef float f32x4 __attribute__((ext_vector_type(4)));

#define MFMA16(a, b, c) __builtin_amdgcn_mfma_f32_16x16x32_bf16((a), (b), (c), 0, 0, 0)

__device__ __forceinline__ float b2f(short s) {
    union { unsigned int u; float f; } c;
    c.u = ((unsigned int)(unsigned short)s) << 16;
    return c.f;
}
__device__ __forceinline__ short f2b(float f) {
    union { __hip_bfloat16 h; short s; } c;
    c.h = __float2bfloat16(f);
    return c.s;
}
struct HiLo { short hi, lo; };
__device__ __forceinline__ HiLo split2(float v) {
    HiLo r;
    r.hi = f2b(v);
    r.lo = f2b(v - b2f(r.hi));   // exact residual; next 8 mantissa bits
    return r;
}

__device__ __forceinline__ void gl_lds16(const void* g, void* l) {
    __builtin_amdgcn_global_load_lds(
        (const __attribute__((address_space(1))) void*)g,
        (__attribute__((address_space(3))) void*)l, 16, 0, 0);
}

// Tile-major offset for bf16 operand matrices consumed by gemm3:
// X[m][k] lives at ((m>>7)*32 + (k>>5))*4096 + ((k>>3)&3)*1024 + (m&127)*8 + (k&7)

// ---------------------------------------------------------------- prep_all
// One kernel, 2048 blocks x 256 thr:
//   bid <  768 : prep(Wq + LoRA) -> wqt hi/lo tile-major
//   bid < 1024 : prep(Wp)        -> wpt hi/lo tile-major
//   bid >=1024 : split_x         -> xhi/xlo tile-major
__global__ __launch_bounds__(256) void prep_all(
    const float* __restrict__ X, short* __restrict__ Xhi, short* __restrict__ Xlo,
    const float* __restrict__ Wq, const float* __restrict__ Al,
    const float* __restrict__ Bl, short* __restrict__ Wqhi, short* __restrict__ Wqlo,
    const float* __restrict__ Wp, short* __restrict__ Wphi, short* __restrict__ Wplo)
{
    __shared__ float sw[64][68];
    __shared__ float sa[64][8];
    __shared__ float sb[8][64];
    int bid = blockIdx.x;
    int tid = threadIdx.x;

    if (bid >= 1024) {                     // ---- split_x body
        int id = bid - 1024;
        int kc = id & 31, p = id >> 5;
        int row = tid >> 1, half = tid & 1;
        const float* src = &X[((size_t)p * 128 + row) * 1024 + kc * 32 + half * 16];
        f32x4 v[4];
#pragma unroll
        for (int u = 0; u < 4; u++) v[u] = *(const f32x4*)(src + u * 4);
        size_t base = ((size_t)p * 32 + kc) * 4096 + (size_t)(half * 2) * 1024 + row * 8;
#pragma unroll
        for (int u = 0; u < 2; u++) {
            short8 h8, l8;
#pragma unroll
            for (int j = 0; j < 8; j++) {
                HiLo hl = split2(v[u * 2 + (j >> 2)][j & 3]);
                h8[j] = hl.hi; l8[j] = hl.lo;
            }
            *(short8*)&Xhi[base + u * 1024] = h8;
            *(short8*)&Xlo[base + u * 1024] = l8;
        }
        return;
    }

    // ---- prep body (Wq with LoRA, or Wp without)
    const float* W; short *Whi, *Wlo;
    int N, lora, bx, by;
    if (bid < 768) {
        W = Wq; Whi = Wqhi; Wlo = Wqlo; N = N3; lora = 1;
        bx = bid % 48; by = bid / 48;
    } else {
        int id = bid - 768;
        W = Wp; Whi = Wphi; Wlo = Wplo; N = DD; lora = 0;
        bx = id & 15; by = id >> 4;
    }
    int n0 = bx * 64, k0 = by * 64;
#pragma unroll
    for (int p = 0; p < 4; p++) {
        int idx = p * 256 + tid;
        int kr = idx >> 4, ch = idx & 15;
        *(f32x4*)&sw[kr][ch * 4] = *(const f32x4*)&W[(size_t)(k0 + kr) * N + n0 + ch * 4];
    }
    if (lora) {
        if (tid < 64) {
#pragma unroll
            for (int r = 0; r < 8; r++) sa[tid][r] = Al[(k0 + tid) * 8 + r];
        } else if (tid < 128) {
            int c = tid - 64;
#pragma unroll
            for (int r = 0; r < 8; r++) sb[r][c] = Bl[(size_t)r * N + n0 + c];
        }
    }
    __syncthreads();
#pragma unroll
    for (int p = 0; p < 2; p++) {
        int idx = p * 256 + tid;
        int nr = idx >> 3, ch = idx & 7;
        short8 h8, l8;
#pragma unroll
        for (int j = 0; j < 8; j++) {
            int k = ch * 8 + j;
            float v = sw[k][nr];
            if (lora) {
                float a2 = 0.f;
#pragma unroll
                for (int r = 0; r < 8; r++) a2 += sa[k][r] * sb[r][nr];
                v += 8.0f * a2;
            }
            HiLo hl = split2(v);
            h8[j] = hl.hi;
            l8[j] = hl.lo;
        }
        int n = n0 + nr;
        int kchunk = (k0 >> 5) + (ch >> 2);
        size_t off = ((size_t)(n >> 7) * 32 + kchunk) * 4096 +
                     (size_t)(ch & 3) * 1024 + (n & 127) * 8;
        *(short8*)&Whi[off] = h8;
        *(short8*)&Wlo[off] = l8;
    }
}

// ---------------------------------------------------------------- gemm3
// C[m][n] = sum_k (Ahi+Alo)[m][k]*(Bhi+Blo)[n][k] (3-term hi/lo) + bias[n].
// Double-buffered LDS; K-step t+1's 8 gl_lds16 issued before t's compute;
// one barrier per K-step. mode 0 (QKV): n<1024 -> qf = v*0.125 (fp32);
// 1024..2047 -> khi/klo bf16 split, attn-LDS layout (key-slot XOR-swizzled);
// >=2048 -> vt bf16, attn-LDS layout (hd-slot XOR-swizzled).
// mode 1 (proj): outf32 row-major.
__global__ __launch_bounds__(256) void gemm3(
    const short* __restrict__ Ahi, const short* __restrict__ Alo,
    const short* __restrict__ Bhi, const short* __restrict__ Blo,
    const float* __restrict__ bias,
    float* __restrict__ qf, short* __restrict__ khi, short* __restrict__ klo,
    short* __restrict__ vt, float* __restrict__ outf32, int N, int mode)
{
    __shared__ short lds[2][4][4][128][8];  // [dbuf][mat(Ah,Al,Bh,Bl)][q4][row][j]
    int tid = threadIdx.x;
    int wav = tid >> 6, lane = tid & 63;
    int l15 = lane & 15, q4 = lane >> 4;
    int wm = wav & 1, wn = wav >> 1;
    int n0 = blockIdx.x * 128, m0 = blockIdx.y * 128;

    const short* ga_h = Ahi + ((size_t)blockIdx.y * 32) * 4096 + tid * 8;
    const short* ga_l = Alo + ((size_t)blockIdx.y * 32) * 4096 + tid * 8;
    const short* gb_h = Bhi + ((size_t)blockIdx.x * 32) * 4096 + tid * 8;
    const short* gb_l = Blo + ((size_t)blockIdx.x * 32) * 4096 + tid * 8;
    short* l0 = &lds[0][0][0][0][0] + tid * 8;

    f32x4 acc[4][4] = {};

#define STAGE(kc_, buf_)                                         \
    {                                                            \
        int koff_ = (kc_) * 4096;                                \
        short* lb_ = l0 + (buf_) * 16384;                        \
        gl_lds16(ga_h + koff_,        lb_);                      \
        gl_lds16(ga_h + koff_ + 2048, lb_ + 2048);               \
        gl_lds16(ga_l + koff_,        lb_ + 4096);               \
        gl_lds16(ga_l + koff_ + 2048, lb_ + 6144);               \
        gl_lds16(gb_h + koff_,        lb_ + 8192);               \
        gl_lds16(gb_h + koff_ + 2048, lb_ + 10240);              \
        gl_lds16(gb_l + koff_,        lb_ + 12288);              \
        gl_lds16(gb_l + koff_ + 2048, lb_ + 14336);              \
    }

    STAGE(0, 0);
    __syncthreads();               // implicit vmcnt(0): K-step 0 staged

    for (int kc = 0; kc < 32; ++kc) {
        int cur = kc & 1;
        if (kc + 1 < 32) STAGE(kc + 1, cur ^ 1);   // travels under compute
        short8 ah[4], al_[4], bh[4], bl[4];
#pragma unroll
        for (int i = 0; i < 4; i++) {
            ah[i]  = *(short8*)&lds[cur][0][q4][wm * 64 + i * 16 + l15][0];
            al_[i] = *(short8*)&lds[cur][1][q4][wm * 64 + i * 16 + l15][0];
            bh[i]  = *(short8*)&lds[cur][2][q4][wn * 64 + i * 16 + l15][0];
            bl[i]  = *(short8*)&lds[cur][3][q4][wn * 64 + i * 16 + l15][0];
        }
#pragma unroll
        for (int mi = 0; mi < 4; mi++)
#pragma unroll
            for (int ni = 0; ni < 4; ni++) {
                acc[mi][ni] = MFMA16(ah[mi], bh[ni], acc[mi][ni]);
                acc[mi][ni] = MFMA16(ah[mi], bl[ni], acc[mi][ni]);
                acc[mi][ni] = MFMA16(al_[mi], bh[ni], acc[mi][ni]);
            }
        __syncthreads();           // drains K+1 loads (issued pre-compute) +
                                   // all waves done reading lds[cur]
    }
#undef STAGE
#pragma unroll
    for (int ni = 0; ni < 4; ni++) {
        int n = n0 + wn * 64 + ni * 16 + l15;
        float bv = bias[n];
#pragma unroll
        for (int mi = 0; mi < 4; mi++) {
            int mbase = m0 + wm * 64 + mi * 16 + q4 * 4;
#pragma unroll
            for (int r = 0; r < 4; r++) {
                int m = mbase + r;
                float v = acc[mi][ni][r] + bv;
                if (mode != 0) {
                    outf32[(size_t)m * 1024 + n] = v;
                } else if (n0 < 1024) {
                    qf[(size_t)m * 1024 + n] = v * 0.125f;   // pow2: exact
                } else if (n0 < 2048) {
                    int kk = n - 1024, hh = kk >> 6, hd = kk & 63;
                    int bb_ = m >> 11, s = m & 2047;
                    int oct = hd >> 3;
                    size_t base = ((size_t)((bb_ << 4) + hh) * 32 + (s >> 6)) * 4096
                                  + (size_t)oct * 512 + ((s & 63) ^ oct) * 8 + (hd & 7);
                    HiLo hl = split2(v);
                    khi[base] = hl.hi;
                    klo[base] = hl.lo;
                } else {
                    int kk = n - 2048, hh = kk >> 6, hd = kk & 63;
                    int bb_ = m >> 11, s = m & 2047;
                    int oct = (s >> 3) & 7;
                    size_t base = ((size_t)((bb_ << 4) + hh) * 32 + (s >> 6)) * 4096
                                  + (size_t)oct * 512 + (hd ^ oct) * 8 + (s & 7);
                    vt[base] = f2b(v);
                }
            }
        }
    }
}

// ---------------------------------------------------------------- attn_mfma
// grid (16, H, B) = 512 blocks x 256 thr. Block x FUSES q-tiles A=31-x and
// B=x into one chunk loop over c=0..31-x: every chunk updates tile A; c<=x
// also updates tile B (B's chunks are a subset of A's). Staging/barriers
// 34 -> 32-x per block (avg -28%); compute unchanged. Per-tile math
// byte-identical to R23: dbuf K/V (6 gl_lds16/chunk), swapped QK^T
// (mfma(K,Q)), in-lane softmax + 2 shfl_xor, two-phase Pt (4.3KB).
__global__ __launch_bounds__(256) void attn_mfma(const float* __restrict__ qf,
                                                 const short* __restrict__ khi,
                                                 const short* __restrict__ klo,
                                                 const short* __restrict__ vtg,
                                                 short* __restrict__ ctxhi,
                                                 short* __restrict__ ctxlo) {
    __shared__ short KhL[2][4096];      // [buf][oct*512 + (key^oct)*8 + (hd&7)]
    __shared__ short KlL[2][4096];
    __shared__ short VtL[2][4096];      // [buf][oct*512 + (hd^oct)*8 + (key&7)]
    __shared__ short Pt[4][4][17][8];   // [wave][key-octet%4][qrow(+pad)][j]

    int h = blockIdx.y, b = blockIdx.z;
    int tid = threadIdx.x, wav = tid >> 6, lane = tid & 63;
    int l15 = lane & 15, q4 = lane >> 4;
    const float* bq = qf + (size_t)b * SS * 1024;
    size_t hb = (size_t)((b * 16 + h) * 32) * 4096;
    const short* gkh = khi + hb;
    const short* gkl = klo + hb;
    const short* gvt = vtg + hb;
    int t8 = tid * 8;

#define ISSUE(c, buf)                                                   \
    {                                                                   \
        size_t co_ = (size_t)(c) * 4096 + t8;                           \
        gl_lds16(gkh + co_,        &KhL[buf][t8]);                      \
        gl_lds16(gkh + co_ + 2048, &KhL[buf][t8 + 2048]);               \
        gl_lds16(gkl + co_,        &KlL[buf][t8]);                      \
        gl_lds16(gkl + co_ + 2048, &KlL[buf][t8 + 2048]);               \
        gl_lds16(gvt + co_,        &VtL[buf][t8]);                      \
        gl_lds16(gvt + co_ + 2048, &VtL[buf][t8 + 2048]);               \
    }

#define LOADQ(qb_, q0h_, q0l_, q1h_, q1l_)                                   \
    {                                                                        \
        size_t qoff_ = (size_t)((qb_) + wav * 16 + l15) * 1024 + h * 64;     \
        f32x4 a0_ = *(const f32x4*)&bq[qoff_ + q4 * 8];                      \
        f32x4 a1_ = *(const f32x4*)&bq[qoff_ + q4 * 8 + 4];                  \
        f32x4 c0_ = *(const f32x4*)&bq[qoff_ + 32 + q4 * 8];                 \
        f32x4 c1_ = *(const f32x4*)&bq[qoff_ + 32 + q4 * 8 + 4];             \
        _Pragma("unroll") for (int j_ = 0; j_ < 4; j_++) {                   \
            HiLo u_ = split2(a0_[j_]); q0h_[j_] = u_.hi; q0l_[j_] = u_.lo;   \
            HiLo v_ = split2(a1_[j_]); q0h_[4 + j_] = v_.hi; q0l_[4 + j_] = v_.lo; \
            HiLo w_ = split2(c0_[j_]); q1h_[j_] = w_.hi; q1l_[j_] = w_.lo;   \
            HiLo z_ = split2(c1_[j_]); q1h_[4 + j_] = z_.hi; q1l_[4 + j_] = z_.lo; \
        }                                                                    \
    }

// One chunk's update for one q-tile (byte-identical math to R23's body).
// Ambient: c, cur, k0, KhL/KlL/VtL/Pt, wav/l15/q4.
#define TILE_STEP(qt_, qb_, q0h_, q0l_, q1h_, q1l_, o_, msc_, lsc_)          \
    {                                                                        \
        f32x4 s_[4];                                                         \
        __builtin_amdgcn_s_setprio(1);                                       \
        _Pragma("unroll") for (int g_ = 0; g_ < 4; g_++) {                   \
            int ko_  = q4 * 512 + ((g_ * 16 + l15) ^ q4) * 8;                \
            int ko2_ = (4 + q4) * 512 + ((g_ * 16 + l15) ^ (4 + q4)) * 8;    \
            short8 k0h_ = *(short8*)&KhL[cur][ko_];                          \
            short8 k0l_ = *(short8*)&KlL[cur][ko_];                          \
            short8 k1h_ = *(short8*)&KhL[cur][ko2_];                         \
            short8 k1l_ = *(short8*)&KlL[cur][ko2_];                         \
            f32x4 acc_ = {};                                                 \
            acc_ = MFMA16(k0h_, q0h_, acc_);                                 \
            acc_ = MFMA16(k0l_, q0h_, acc_);                                 \
            acc_ = MFMA16(k0h_, q0l_, acc_);                                 \
            acc_ = MFMA16(k1h_, q1h_, acc_);                                 \
            acc_ = MFMA16(k1l_, q1h_, acc_);                                 \
            acc_ = MFMA16(k1h_, q1l_, acc_);                                 \
            s_[g_] = acc_;                                                   \
        }                                                                    \
        __builtin_amdgcn_s_setprio(0);                                       \
        if (c == (qt_)) {                                                    \
            int q_ = (qb_) + wav * 16 + l15;                                 \
            _Pragma("unroll") for (int g_ = 0; g_ < 4; g_++)                 \
                _Pragma("unroll") for (int r_ = 0; r_ < 4; r_++)             \
                    if (k0 + g_ * 16 + q4 * 4 + r_ > q_) s_[g_][r_] = -1e30f;\
        }                                                                    \
        f32x4 mx4_ = s_[0];                                                  \
        _Pragma("unroll") for (int g_ = 1; g_ < 4; g_++) {                   \
            mx4_[0] = fmaxf(mx4_[0], s_[g_][0]);                             \
            mx4_[1] = fmaxf(mx4_[1], s_[g_][1]);                             \
            mx4_[2] = fmaxf(mx4_[2], s_[g_][2]);                             \
            mx4_[3] = fmaxf(mx4_[3], s_[g_][3]);                             \
        }                                                                    \
        float mx_ = fmaxf(fmaxf(mx4_[0], mx4_[1]), fmaxf(mx4_[2], mx4_[3]));\
        mx_ = fmaxf(mx_, __shfl_xor(mx_, 16, 64));                           \
        mx_ = fmaxf(mx_, __shfl_xor(mx_, 32, 64));                           \
        float mn_ = fmaxf(msc_, mx_);                                        \
        f32x4 ps_ = {};                                                      \
        s16x4 pb_[4];                                                        \
        _Pragma("unroll") for (int g_ = 0; g_ < 4; g_++) {                   \
            _Pragma("unroll") for (int r_ = 0; r_ < 4; r_++) {               \
                float p_ = __expf(s_[g_][r_] - mn_);                         \
                ps_[r_] += p_;                                               \
                pb_[g_][r_] = f2b(p_);                                       \
            }                                                                \
        }                                                                    \
        float sm_ = (ps_[0] + ps_[1]) + (ps_[2] + ps_[3]);                   \
        sm_ += __shfl_xor(sm_, 16, 64);                                      \
        sm_ += __shfl_xor(sm_, 32, 64);                                      \
        float alpha_ = __expf(msc_ - mn_);                                   \
        msc_ = mn_;                                                          \
        lsc_ = lsc_ * alpha_ + sm_;                                          \
        float al0_ = __shfl(alpha_, q4 * 4 + 0, 64);                         \
        float al1_ = __shfl(alpha_, q4 * 4 + 1, 64);                         \
        float al2_ = __shfl(alpha_, q4 * 4 + 2, 64);                         \
        float al3_ = __shfl(alpha_, q4 * 4 + 3, 64);                         \
        *(s16x4*)&Pt[wav][0 + (q4 >> 1)][l15][(q4 & 1) * 4] = pb_[0];        \
        *(s16x4*)&Pt[wav][2 + (q4 >> 1)][l15][(q4 & 1) * 4] = pb_[1];        \
        short8 pf0_ = *(short8*)&Pt[wav][q4][l15][0];                        \
        __builtin_amdgcn_s_setprio(1);                                       \
        _Pragma("unroll") for (int gg_ = 0; gg_ < 4; gg_++) {                \
            int vo_ = q4 * 512 + ((gg_ * 16 + l15) ^ q4) * 8;                \
            short8 vf0_ = *(short8*)&VtL[cur][vo_];                          \
            f32x4 tt_ = o_[gg_];                                             \
            tt_[0] *= al0_; tt_[1] *= al1_; tt_[2] *= al2_; tt_[3] *= al3_;  \
            o_[gg_] = MFMA16(pf0_, vf0_, tt_);                               \
        }                                                                    \
        __builtin_amdgcn_s_setprio(0);                                       \
        *(s16x4*)&Pt[wav][0 + (q4 >> 1)][l15][(q4 & 1) * 4] = pb_[2];        \
        *(s16x4*)&Pt[wav][2 + (q4 >> 1)][l15][(q4 & 1) * 4] = pb_[3];        \
        short8 pf1_ = *(short8*)&Pt[wav][q4][l15][0];                        \
        __builtin_amdgcn_s_setprio(1);                                       \
        _Pragma("unroll") for (int gg_ = 0; gg_ < 4; gg_++) {                \
            int vo2_ = (4 + q4) * 512 + ((gg_ * 16 + l15) ^ (4 + q4)) * 8;   \
            short8 vf1_ = *(short8*)&VtL[cur][vo2_];                         \
            o_[gg_] = MFMA16(pf1_, vf1_, o_[gg_]);                           \
        }                                                                    \
        __builtin_amdgcn_s_setprio(0);                                       \
    }

#define WRITE_CTX(qb_, o_, lsc_)                                             \
    {                                                                        \
        float ls0_ = __shfl(lsc_, q4 * 4 + 0, 64);                           \
        float ls1_ = __shfl(lsc_, q4 * 4 + 1, 64);                           \
        float ls2_ = __shfl(lsc_, q4 * 4 + 2, 64);                           \
        float ls3_ = __shfl(lsc_, q4 * 4 + 3, 64);                           \
        float lsr_[4] = {ls0_, ls1_, ls2_, ls3_};                            \
        _Pragma("unroll") for (int gg_ = 0; gg_ < 4; gg_++)                  \
            _Pragma("unroll") for (int r_ = 0; r_ < 4; r_++) {               \
                int q_ = (qb_) + wav * 16 + q4 * 4 + r_;                     \
                int mrow_ = b * SS + q_;                                     \
                int k_ = h * 64 + gg_ * 16 + l15;                            \
                HiLo hl_ = split2(o_[gg_][r_] / lsr_[r_]);                   \
                size_t off_ = ((size_t)(mrow_ >> 7) * 32 + (k_ >> 5)) * 4096 \
                    + (size_t)((k_ >> 3) & 3) * 1024 + (mrow_ & 127) * 8 + (k_ & 7); \
                ctxhi[off_] = hl_.hi;                                        \
                ctxlo[off_] = hl_.lo;                                        \
            }                                                                \
    }

    int x = blockIdx.x;
    int qtA = 31 - x, qtB = x;
    int qbA = qtA * 64, qbB = qtB * 64;

    short8 qA0h, qA0l, qA1h, qA1l, qB0h, qB0l, qB1h, qB1l;
    LOADQ(qbA, qA0h, qA0l, qA1h, qA1l);
    LOADQ(qbB, qB0h, qB0l, qB1h, qB1l);

    f32x4 oA[4] = {}, oB[4] = {};
    float mscA = -1e30f, lscA = 0.f, mscB = -1e30f, lscB = 0.f;
    int nch = qtA + 1;

    ISSUE(0, 0);
    __syncthreads();    // implicit vmcnt(0): chunk 0 staged

    for (int c = 0; c < nch; ++c) {
        int cur = c & 1;
        int k0 = c * 64;

        if (c + 1 < nch) ISSUE(c + 1, cur ^ 1);

        TILE_STEP(qtA, qbA, qA0h, qA0l, qA1h, qA1l, oA, mscA, lscA);
        if (c <= qtB)
            TILE_STEP(qtB, qbB, qB0h, qB0l, qB1h, qB1l, oB, mscB, lscB);

        __syncthreads();   // drains next-chunk gl_lds; orders buffer reuse
    }

    WRITE_CTX(qbA, oA, lscA);
    WRITE_CTX(qbB, oB, lscB);
#undef ISSUE
#undef LOADQ
#undef TILE_STEP
#undef WRITE_CTX
}

extern "C" void kernel_launch(void* const* d_in, const int* in_sizes, int n_in,
                              void* d_out, int out_size, void* d_ws, size_t ws_size,
                              hipStream_t stream) {
    const float* x  = (const float*)d_in[0];
    const float* Wq = (const float*)d_in[1];
    const float* bq = (const float*)d_in[2];
    const float* Al = (const float*)d_in[3];
    const float* Bl = (const float*)d_in[4];
    const float* Wp = (const float*)d_in[5];
    const float* bp = (const float*)d_in[6];

    char* ws = (char*)d_ws;
    float* qf     = (float*)(ws);                             // 0-16 MB
    short* khi    = (short*)(ws + (size_t)16 * 1024 * 1024);  // 16-24
    short* klo    = (short*)(ws + (size_t)24 * 1024 * 1024);  // 24-32
    short* vt     = (short*)(ws + (size_t)32 * 1024 * 1024);  // 32-40
    short* wpt_hi = (short*)(ws + (size_t)40 * 1024 * 1024);  // 40-42
    short* wpt_lo = (short*)(ws + (size_t)42 * 1024 * 1024);  // 42-44
    short* wqt_hi = (short*)(ws + (size_t)44 * 1024 * 1024);  // 44-50
    short* wqt_lo = (short*)(ws + (size_t)50 * 1024 * 1024);  // 50-56
    short* xhi    = (short*)(ws + (size_t)56 * 1024 * 1024);  // 56-64
    short* xlo    = (short*)(ws + (size_t)64 * 1024 * 1024);  // 64-72
    short* ctxhi  = (short*)(ws + (size_t)44 * 1024 * 1024);  // 44-52 (overlays dead wqt_hi)
    short* ctxlo  = (short*)(ws + (size_t)52 * 1024 * 1024);  // 52-60 (overlays dead wqt_lo/xhi)

    hipLaunchKernelGGL(prep_all, dim3(2048), dim3(256), 0, stream,
                       x, xhi, xlo, Wq, Al, Bl, wqt_hi, wqt_lo,
                       Wp, wpt_hi, wpt_lo);
    hipLaunchKernelGGL(gemm3, dim3(N3 / 128, MR / 128), dim3(256), 0, stream,
                       xhi, xlo, wqt_hi, wqt_lo, bq,
                       qf, khi, klo, vt, (float*)nullptr, N3, 0);
    hipLaunchKernelGGL(attn_mfma, dim3(SS / 128, HH, BB), dim3(256), 0, stream,
                       qf, khi, klo, vt, ctxhi, ctxlo);
    hipLaunchKernelGGL(gemm3, dim3(DD / 128, MR / 128), dim3(256), 0, stream,
                       ctxhi, ctxlo, wpt_hi, wpt_lo, bp,
                       (float*)nullptr, (short*)nullptr, (short*)nullptr,
                       (short*)nullptr, (float*)d_out, DD, 1);
}

// Round 14
// 270.744 us; speedup vs baseline: 1.0714x; 1.0032x over previous
//
#include <hip/hip_runtime.h>
#include <hip/hip_bf16.h>

// B=2, S=2048, D=1024, H=16, HD=64, RANK=8, ALPHA=8. ALL I/O FP32.
// R26 = R25 with ONE change: proj gemm gets its own kernel (gemm_proj,
// 128m x 64n tile, grid 16x32 = 512 blocks -> 2 blocks/CU co-resident;
// was gemm3 at 8x32 = 256 blocks = 1/CU with every barrier drain exposed).
// LDS 48KB dbuf; staging 6 linear gl_lds16/thread/k-step; 24 MFMA/k-step
// (acc[4][2], 3 hi/lo terms -- numerics byte-identical).
// prep_all/gemm3(QKV)/attn byte-identical to R25.
// ws (72 MB): qf 0-16 | khi 16-24 | klo 24-32 | vt 32-40 |
//             wpt hi 40-42 lo 42-44 | wqt hi 44-50 lo 50-56 |
//             xhi 56-64 xlo 64-72 | ctxhi 44-52 ctxlo 52-60 (overlay dead).

#define BB    2
#define SS    2048
#define DD    1024
#define HH    16
#define HDIM  64
#define N3    3072
#define MR    4096

typedef short short8 __attribute__((ext_vector_type(8)));
typedef short s16x4 __attribute__((ext_vector_type(4)));
typedef float f32x4 __attribute__((ext_vector_type(4)));

#define MFMA16(a, b, c) __builtin_amdgcn_mfma_f32_16x16x32_bf16((a), (b), (c), 0, 0, 0)

__device__ __forceinline__ float b2f(short s) {
    union { unsigned int u; float f; } c;
    c.u = ((unsigned int)(unsigned short)s) << 16;
    return c.f;
}
__device__ __forceinline__ short f2b(float f) {
    union { __hip_bfloat16 h; short s; } c;
    c.h = __float2bfloat16(f);
    return c.s;
}
struct HiLo { short hi, lo; };
__device__ __forceinline__ HiLo split2(float v) {
    HiLo r;
    r.hi = f2b(v);
    r.lo = f2b(v - b2f(r.hi));   // exact residual; next 8 mantissa bits
    return r;
}

__device__ __forceinline__ void gl_lds16(const void* g, void* l) {
    __builtin_amdgcn_global_load_lds(
        (const __attribute__((address_space(1))) void*)g,
        (__attribute__((address_space(3))) void*)l, 16, 0, 0);
}

// Tile-major offset for bf16 operand matrices consumed by gemm3/gemm_proj:
// X[m][k] lives at ((m>>7)*32 + (k>>5))*4096 + ((k>>3)&3)*1024 + (m&127)*8 + (k&7)

// ---------------------------------------------------------------- prep_all
// One kernel, 2048 blocks x 256 thr:
//   bid <  768 : prep(Wq + LoRA) -> wqt hi/lo tile-major
//   bid < 1024 : prep(Wp)        -> wpt hi/lo tile-major
//   bid >=1024 : split_x         -> xhi/xlo tile-major
__global__ __launch_bounds__(256) void prep_all(
    const float* __restrict__ X, short* __restrict__ Xhi, short* __restrict__ Xlo,
    const float* __restrict__ Wq, const float* __restrict__ Al,
    const float* __restrict__ Bl, short* __restrict__ Wqhi, short* __restrict__ Wqlo,
    const float* __restrict__ Wp, short* __restrict__ Wphi, short* __restrict__ Wplo)
{
    __shared__ float sw[64][68];
    __shared__ float sa[64][8];
    __shared__ float sb[8][64];
    int bid = blockIdx.x;
    int tid = threadIdx.x;

    if (bid >= 1024) {                     // ---- split_x body
        int id = bid - 1024;
        int kc = id & 31, p = id >> 5;
        int row = tid >> 1, half = tid & 1;
        const float* src = &X[((size_t)p * 128 + row) * 1024 + kc * 32 + half * 16];
        f32x4 v[4];
#pragma unroll
        for (int u = 0; u < 4; u++) v[u] = *(const f32x4*)(src + u * 4);
        size_t base = ((size_t)p * 32 + kc) * 4096 + (size_t)(half * 2) * 1024 + row * 8;
#pragma unroll
        for (int u = 0; u < 2; u++) {
            short8 h8, l8;
#pragma unroll
            for (int j = 0; j < 8; j++) {
                HiLo hl = split2(v[u * 2 + (j >> 2)][j & 3]);
                h8[j] = hl.hi; l8[j] = hl.lo;
            }
            *(short8*)&Xhi[base + u * 1024] = h8;
            *(short8*)&Xlo[base + u * 1024] = l8;
        }
        return;
    }

    // ---- prep body (Wq with LoRA, or Wp without)
    const float* W; short *Whi, *Wlo;
    int N, lora, bx, by;
    if (bid < 768) {
        W = Wq; Whi = Wqhi; Wlo = Wqlo; N = N3; lora = 1;
        bx = bid % 48; by = bid / 48;
    } else {
        int id = bid - 768;
        W = Wp; Whi = Wphi; Wlo = Wplo; N = DD; lora = 0;
        bx = id & 15; by = id >> 4;
    }
    int n0 = bx * 64, k0 = by * 64;
#pragma unroll
    for (int p = 0; p < 4; p++) {
        int idx = p * 256 + tid;
        int kr = idx >> 4, ch = idx & 15;
        *(f32x4*)&sw[kr][ch * 4] = *(const f32x4*)&W[(size_t)(k0 + kr) * N + n0 + ch * 4];
    }
    if (lora) {
        if (tid < 64) {
#pragma unroll
            for (int r = 0; r < 8; r++) sa[tid][r] = Al[(k0 + tid) * 8 + r];
        } else if (tid < 128) {
            int c = tid - 64;
#pragma unroll
            for (int r = 0; r < 8; r++) sb[r][c] = Bl[(size_t)r * N + n0 + c];
        }
    }
    __syncthreads();
#pragma unroll
    for (int p = 0; p < 2; p++) {
        int idx = p * 256 + tid;
        int nr = idx >> 3, ch = idx & 7;
        short8 h8, l8;
#pragma unroll
        for (int j = 0; j < 8; j++) {
            int k = ch * 8 + j;
            float v = sw[k][nr];
            if (lora) {
                float a2 = 0.f;
#pragma unroll
                for (int r = 0; r < 8; r++) a2 += sa[k][r] * sb[r][nr];
                v += 8.0f * a2;
            }
            HiLo hl = split2(v);
            h8[j] = hl.hi;
            l8[j] = hl.lo;
        }
        int n = n0 + nr;
        int kchunk = (k0 >> 5) + (ch >> 2);
        size_t off = ((size_t)(n >> 7) * 32 + kchunk) * 4096 +
                     (size_t)(ch & 3) * 1024 + (n & 127) * 8;
        *(short8*)&Whi[off] = h8;
        *(short8*)&Wlo[off] = l8;
    }
}

// ---------------------------------------------------------------- gemm3
// QKV gemm. C[m][n] = sum_k (Ahi+Alo)[m][k]*(Bhi+Blo)[n][k] + bias[n].
// Double-buffered LDS; K-step t+1's 8 gl_lds16 issued before t's compute;
// one barrier per K-step. n<1024 -> qf = v*0.125 (fp32); 1024..2047 ->
// khi/klo bf16 split, attn-LDS layout (key-slot XOR-swizzled); >=2048 ->
// vt bf16, attn-LDS layout (hd-slot XOR-swizzled).
__global__ __launch_bounds__(256) void gemm3(
    const short* __restrict__ Ahi, const short* __restrict__ Alo,
    const short* __restrict__ Bhi, const short* __restrict__ Blo,
    const float* __restrict__ bias,
    float* __restrict__ qf, short* __restrict__ khi, short* __restrict__ klo,
    short* __restrict__ vt, float* __restrict__ outf32, int N, int mode)
{
    __shared__ short lds[2][4][4][128][8];  // [dbuf][mat(Ah,Al,Bh,Bl)][q4][row][j]
    int tid = threadIdx.x;
    int wav = tid >> 6, lane = tid & 63;
    int l15 = lane & 15, q4 = lane >> 4;
    int wm = wav & 1, wn = wav >> 1;
    int n0 = blockIdx.x * 128, m0 = blockIdx.y * 128;

    const short* ga_h = Ahi + ((size_t)blockIdx.y * 32) * 4096 + tid * 8;
    const short* ga_l = Alo + ((size_t)blockIdx.y * 32) * 4096 + tid * 8;
    const short* gb_h = Bhi + ((size_t)blockIdx.x * 32) * 4096 + tid * 8;
    const short* gb_l = Blo + ((size_t)blockIdx.x * 32) * 4096 + tid * 8;
    short* l0 = &lds[0][0][0][0][0] + tid * 8;

    f32x4 acc[4][4] = {};

#define STAGE(kc_, buf_)                                         \
    {                                                            \
        int koff_ = (kc_) * 4096;                                \
        short* lb_ = l0 + (buf_) * 16384;                        \
        gl_lds16(ga_h + koff_,        lb_);                      \
        gl_lds16(ga_h + koff_ + 2048, lb_ + 2048);               \
        gl_lds16(ga_l + koff_,        lb_ + 4096);               \
        gl_lds16(ga_l + koff_ + 2048, lb_ + 6144);               \
        gl_lds16(gb_h + koff_,        lb_ + 8192);               \
        gl_lds16(gb_h + koff_ + 2048, lb_ + 10240);              \
        gl_lds16(gb_l + koff_,        lb_ + 12288);              \
        gl_lds16(gb_l + koff_ + 2048, lb_ + 14336);              \
    }

    STAGE(0, 0);
    __syncthreads();               // implicit vmcnt(0): K-step 0 staged

    for (int kc = 0; kc < 32; ++kc) {
        int cur = kc & 1;
        if (kc + 1 < 32) STAGE(kc + 1, cur ^ 1);   // travels under compute
        short8 ah[4], al_[4], bh[4], bl[4];
#pragma unroll
        for (int i = 0; i < 4; i++) {
            ah[i]  = *(short8*)&lds[cur][0][q4][wm * 64 + i * 16 + l15][0];
            al_[i] = *(short8*)&lds[cur][1][q4][wm * 64 + i * 16 + l15][0];
            bh[i]  = *(short8*)&lds[cur][2][q4][wn * 64 + i * 16 + l15][0];
            bl[i]  = *(short8*)&lds[cur][3][q4][wn * 64 + i * 16 + l15][0];
        }
#pragma unroll
        for (int mi = 0; mi < 4; mi++)
#pragma unroll
            for (int ni = 0; ni < 4; ni++) {
                acc[mi][ni] = MFMA16(ah[mi], bh[ni], acc[mi][ni]);
                acc[mi][ni] = MFMA16(ah[mi], bl[ni], acc[mi][ni]);
                acc[mi][ni] = MFMA16(al_[mi], bh[ni], acc[mi][ni]);
            }
        __syncthreads();           // drains K+1 loads (issued pre-compute) +
                                   // all waves done reading lds[cur]
    }
#undef STAGE
#pragma unroll
    for (int ni = 0; ni < 4; ni++) {
        int n = n0 + wn * 64 + ni * 16 + l15;
        float bv = bias[n];
#pragma unroll
        for (int mi = 0; mi < 4; mi++) {
            int mbase = m0 + wm * 64 + mi * 16 + q4 * 4;
#pragma unroll
            for (int r = 0; r < 4; r++) {
                int m = mbase + r;
                float v = acc[mi][ni][r] + bv;
                if (mode != 0) {
                    outf32[(size_t)m * 1024 + n] = v;
                } else if (n0 < 1024) {
                    qf[(size_t)m * 1024 + n] = v * 0.125f;   // pow2: exact
                } else if (n0 < 2048) {
                    int kk = n - 1024, hh = kk >> 6, hd = kk & 63;
                    int bb_ = m >> 11, s = m & 2047;
                    int oct = hd >> 3;
                    size_t base = ((size_t)((bb_ << 4) + hh) * 32 + (s >> 6)) * 4096
                                  + (size_t)oct * 512 + ((s & 63) ^ oct) * 8 + (hd & 7);
                    HiLo hl = split2(v);
                    khi[base] = hl.hi;
                    klo[base] = hl.lo;
                } else {
                    int kk = n - 2048, hh = kk >> 6, hd = kk & 63;
                    int bb_ = m >> 11, s = m & 2047;
                    int oct = (s >> 3) & 7;
                    size_t base = ((size_t)((bb_ << 4) + hh) * 32 + (s >> 6)) * 4096
                                  + (size_t)oct * 512 + (hd ^ oct) * 8 + (s & 7);
                    vt[base] = f2b(v);
                }
            }
        }
    }
}

// ---------------------------------------------------------------- gemm_proj
// out[m][n] = sum_k (Ahi+Alo)[m][k]*(Bhi+Blo)[n][k] + bias[n], fp32 out.
// 128m x 64n tile -> grid (16, 32) = 512 blocks = 2 blocks/CU (48KB LDS
// dbuf), so a co-resident block covers each k-step's barrier drain.
// LDS per buf (shorts): Ah[4][128][8]@0, Al@4096, Bh[4][64][8]@8192,
// Bl@10240 (12288 shorts = 24KB; x2 dbuf).
__global__ __launch_bounds__(256) void gemm_proj(
    const short* __restrict__ Ahi, const short* __restrict__ Alo,
    const short* __restrict__ Bhi, const short* __restrict__ Blo,
    const float* __restrict__ bias, float* __restrict__ out)
{
    __shared__ short lds[2][12288];
    int tid = threadIdx.x;
    int wav = tid >> 6, lane = tid & 63;
    int l15 = lane & 15, q4 = lane >> 4;
    int wm = wav & 1, wn = wav >> 1;
    int bx = blockIdx.x;                  // n-block (64 wide)
    int n0 = bx * 64, m0 = blockIdx.y * 128;
    int rowbase = (bx & 1) * 64;          // B rows within its 128-panel

    const short* ga_h = Ahi + ((size_t)blockIdx.y * 32) * 4096 + tid * 8;
    const short* ga_l = Alo + ((size_t)blockIdx.y * 32) * 4096 + tid * 8;
    size_t boff = ((size_t)(bx >> 1) * 32) * 4096 +
                  (size_t)(tid >> 6) * 1024 + (rowbase + (tid & 63)) * 8;
    const short* gb_h = Bhi + boff;
    const short* gb_l = Blo + boff;
    short* l0 = &lds[0][0] + tid * 8;

    f32x4 acc[4][2] = {};

#define PSTAGE(kc_, buf_)                                        \
    {                                                            \
        int koff_ = (kc_) * 4096;                                \
        short* lb_ = l0 + (buf_) * 12288;                        \
        gl_lds16(ga_h + koff_,        lb_);                      \
        gl_lds16(ga_h + koff_ + 2048, lb_ + 2048);               \
        gl_lds16(ga_l + koff_,        lb_ + 4096);               \
        gl_lds16(ga_l + koff_ + 2048, lb_ + 6144);               \
        gl_lds16(gb_h + koff_,        lb_ + 8192);               \
        gl_lds16(gb_l + koff_,        lb_ + 10240);              \
    }

    PSTAGE(0, 0);
    __syncthreads();               // implicit vmcnt(0): K-step 0 staged

    for (int kc = 0; kc < 32; ++kc) {
        int cur = kc & 1;
        if (kc + 1 < 32) PSTAGE(kc + 1, cur ^ 1);  // travels under compute
        short* Lb = &lds[cur][0];
        short8 ah[4], al_[4], bh[2], bl[2];
#pragma unroll
        for (int i = 0; i < 4; i++) {
            int ro = q4 * 1024 + (wm * 64 + i * 16 + l15) * 8;
            ah[i]  = *(short8*)&Lb[ro];
            al_[i] = *(short8*)&Lb[4096 + ro];
        }
#pragma unroll
        for (int i = 0; i < 2; i++) {
            int ro = q4 * 512 + (wn * 32 + i * 16 + l15) * 8;
            bh[i] = *(short8*)&Lb[8192 + ro];
            bl[i] = *(short8*)&Lb[10240 + ro];
        }
#pragma unroll
        for (int mi = 0; mi < 4; mi++)
#pragma unroll
            for (int ni = 0; ni < 2; ni++) {
                acc[mi][ni] = MFMA16(ah[mi], bh[ni], acc[mi][ni]);
                acc[mi][ni] = MFMA16(ah[mi], bl[ni], acc[mi][ni]);
                acc[mi][ni] = MFMA16(al_[mi], bh[ni], acc[mi][ni]);
            }
        __syncthreads();
    }
#undef PSTAGE
#pragma unroll
    for (int ni = 0; ni < 2; ni++) {
        int n = n0 + wn * 32 + ni * 16 + l15;
        float bv = bias[n];
#pragma unroll
        for (int mi = 0; mi < 4; mi++) {
            int mbase = m0 + wm * 64 + mi * 16 + q4 * 4;
#pragma unroll
            for (int r = 0; r < 4; r++)
                out[(size_t)(mbase + r) * 1024 + n] = acc[mi][ni][r] + bv;
        }
    }
}

// ---------------------------------------------------------------- attn_mfma
// grid (16, H, B) = 512 blocks x 256 thr. Block x FUSES q-tiles A=31-x and
// B=x into one chunk loop over c=0..31-x: every chunk updates tile A; c<=x
// also updates tile B (B's chunks are a subset of A's). Per-tile math
// byte-identical to R23: dbuf K/V (6 gl_lds16/chunk), swapped QK^T
// (mfma(K,Q)), in-lane softmax + 2 shfl_xor, two-phase Pt (4.3KB).
__global__ __launch_bounds__(256) void attn_mfma(const float* __restrict__ qf,
                                                 const short* __restrict__ khi,
                                                 const short* __restrict__ klo,
                                                 const short* __restrict__ vtg,
                                                 short* __restrict__ ctxhi,
                                                 short* __restrict__ ctxlo) {
    __shared__ short KhL[2][4096];      // [buf][oct*512 + (key^oct)*8 + (hd&7)]
    __shared__ short KlL[2][4096];
    __shared__ short VtL[2][4096];      // [buf][oct*512 + (hd^oct)*8 + (key&7)]
    __shared__ short Pt[4][4][17][8];   // [wave][key-octet%4][qrow(+pad)][j]

    int h = blockIdx.y, b = blockIdx.z;
    int tid = threadIdx.x, wav = tid >> 6, lane = tid & 63;
    int l15 = lane & 15, q4 = lane >> 4;
    const float* bq = qf + (size_t)b * SS * 1024;
    size_t hb = (size_t)((b * 16 + h) * 32) * 4096;
    const short* gkh = khi + hb;
    const short* gkl = klo + hb;
    const short* gvt = vtg + hb;
    int t8 = tid * 8;

#define ISSUE(c, buf)                                                   \
    {                                                                   \
        size_t co_ = (size_t)(c) * 4096 + t8;                           \
        gl_lds16(gkh + co_,        &KhL[buf][t8]);                      \
        gl_lds16(gkh + co_ + 2048, &KhL[buf][t8 + 2048]);               \
        gl_lds16(gkl + co_,        &KlL[buf][t8]);                      \
        gl_lds16(gkl + co_ + 2048, &KlL[buf][t8 + 2048]);               \
        gl_lds16(gvt + co_,        &VtL[buf][t8]);                      \
        gl_lds16(gvt + co_ + 2048, &VtL[buf][t8 + 2048]);               \
    }

#define LOADQ(qb_, q0h_, q0l_, q1h_, q1l_)                                   \
    {                                                                        \
        size_t qoff_ = (size_t)((qb_) + wav * 16 + l15) * 1024 + h * 64;     \
        f32x4 a0_ = *(const f32x4*)&bq[qoff_ + q4 * 8];                      \
        f32x4 a1_ = *(const f32x4*)&bq[qoff_ + q4 * 8 + 4];                  \
        f32x4 c0_ = *(const f32x4*)&bq[qoff_ + 32 + q4 * 8];                 \
        f32x4 c1_ = *(const f32x4*)&bq[qoff_ + 32 + q4 * 8 + 4];             \
        _Pragma("unroll") for (int j_ = 0; j_ < 4; j_++) {                   \
            HiLo u_ = split2(a0_[j_]); q0h_[j_] = u_.hi; q0l_[j_] = u_.lo;   \
            HiLo v_ = split2(a1_[j_]); q0h_[4 + j_] = v_.hi; q0l_[4 + j_] = v_.lo; \
            HiLo w_ = split2(c0_[j_]); q1h_[j_] = w_.hi; q1l_[j_] = w_.lo;   \
            HiLo z_ = split2(c1_[j_]); q1h_[4 + j_] = z_.hi; q1l_[4 + j_] = z_.lo; \
        }                                                                    \
    }

// One chunk's update for one q-tile (byte-identical math to R23's body).
// Ambient: c, cur, k0, KhL/KlL/VtL/Pt, wav/l15/q4.
#define TILE_STEP(qt_, qb_, q0h_, q0l_, q1h_, q1l_, o_, msc_, lsc_)          \
    {                                                                        \
        f32x4 s_[4];                                                         \
        __builtin_amdgcn_s_setprio(1);                                       \
        _Pragma("unroll") for (int g_ = 0; g_ < 4; g_++) {                   \
            int ko_  = q4 * 512 + ((g_ * 16 + l15) ^ q4) * 8;                \
            int ko2_ = (4 + q4) * 512 + ((g_ * 16 + l15) ^ (4 + q4)) * 8;    \
            short8 k0h_ = *(short8*)&KhL[cur][ko_];                          \
            short8 k0l_ = *(short8*)&KlL[cur][ko_];                          \
            short8 k1h_ = *(short8*)&KhL[cur][ko2_];                         \
            short8 k1l_ = *(short8*)&KlL[cur][ko2_];                         \
            f32x4 acc_ = {};                                                 \
            acc_ = MFMA16(k0h_, q0h_, acc_);                                 \
            acc_ = MFMA16(k0l_, q0h_, acc_);                                 \
            acc_ = MFMA16(k0h_, q0l_, acc_);                                 \
            acc_ = MFMA16(k1h_, q1h_, acc_);                                 \
            acc_ = MFMA16(k1l_, q1h_, acc_);                                 \
            acc_ = MFMA16(k1h_, q1l_, acc_);                                 \
            s_[g_] = acc_;                                                   \
        }                                                                    \
        __builtin_amdgcn_s_setprio(0);                                       \
        if (c == (qt_)) {                                                    \
            int q_ = (qb_) + wav * 16 + l15;                                 \
            _Pragma("unroll") for (int g_ = 0; g_ < 4; g_++)                 \
                _Pragma("unroll") for (int r_ = 0; r_ < 4; r_++)             \
                    if (k0 + g_ * 16 + q4 * 4 + r_ > q_) s_[g_][r_] = -1e30f;\
        }                                                                    \
        f32x4 mx4_ = s_[0];                                                  \
        _Pragma("unroll") for (int g_ = 1; g_ < 4; g_++) {                   \
            mx4_[0] = fmaxf(mx4_[0], s_[g_][0]);                             \
            mx4_[1] = fmaxf(mx4_[1], s_[g_][1]);                             \
            mx4_[2] = fmaxf(mx4_[2], s_[g_][2]);                             \
            mx4_[3] = fmaxf(mx4_[3], s_[g_][3]);                             \
        }                                                                    \
        float mx_ = fmaxf(fmaxf(mx4_[0], mx4_[1]), fmaxf(mx4_[2], mx4_[3]));\
        mx_ = fmaxf(mx_, __shfl_xor(mx_, 16, 64));                           \
        mx_ = fmaxf(mx_, __shfl_xor(mx_, 32, 64));                           \
        float mn_ = fmaxf(msc_, mx_);                                        \
        f32x4 ps_ = {};                                                      \
        s16x4 pb_[4];                                                        \
        _Pragma("unroll") for (int g_ = 0; g_ < 4; g_++) {                   \
            _Pragma("unroll") for (int r_ = 0; r_ < 4; r_++) {               \
                float p_ = __expf(s_[g_][r_] - mn_);                         \
                ps_[r_] += p_;                                               \
                pb_[g_][r_] = f2b(p_);                                       \
            }                                                                \
        }                                                                    \
        float sm_ = (ps_[0] + ps_[1]) + (ps_[2] + ps_[3]);                   \
        sm_ += __shfl_xor(sm_, 16, 64);                                      \
        sm_ += __shfl_xor(sm_, 32, 64);                                      \
        float alpha_ = __expf(msc_ - mn_);                                   \
        msc_ = mn_;                                                          \
        lsc_ = lsc_ * alpha_ + sm_;                                          \
        float al0_ = __shfl(alpha_, q4 * 4 + 0, 64);                         \
        float al1_ = __shfl(alpha_, q4 * 4 + 1, 64);                         \
        float al2_ = __shfl(alpha_, q4 * 4 + 2, 64);                         \
        float al3_ = __shfl(alpha_, q4 * 4 + 3, 64);                         \
        *(s16x4*)&Pt[wav][0 + (q4 >> 1)][l15][(q4 & 1) * 4] = pb_[0];        \
        *(s16x4*)&Pt[wav][2 + (q4 >> 1)][l15][(q4 & 1) * 4] = pb_[1];        \
        short8 pf0_ = *(short8*)&Pt[wav][q4][l15][0];                        \
        __builtin_amdgcn_s_setprio(1);                                       \
        _Pragma("unroll") for (int gg_ = 0; gg_ < 4; gg_++) {                \
            int vo_ = q4 * 512 + ((gg_ * 16 + l15) ^ q4) * 8;                \
            short8 vf0_ = *(short8*)&VtL[cur][vo_];                          \
            f32x4 tt_ = o_[gg_];                                             \
            tt_[0] *= al0_; tt_[1] *= al1_; tt_[2] *= al2_; tt_[3] *= al3_;  \
            o_[gg_] = MFMA16(pf0_, vf0_, tt_);                               \
        }                                                                    \
        __builtin_amdgcn_s_setprio(0);                                       \
        *(s16x4*)&Pt[wav][0 + (q4 >> 1)][l15][(q4 & 1) * 4] = pb_[2];        \
        *(s16x4*)&Pt[wav][2 + (q4 >> 1)][l15][(q4 & 1) * 4] = pb_[3];        \
        short8 pf1_ = *(short8*)&Pt[wav][q4][l15][0];                        \
        __builtin_amdgcn_s_setprio(1);                                       \
        _Pragma("unroll") for (int gg_ = 0; gg_ < 4; gg_++) {                \
            int vo2_ = (4 + q4) * 512 + ((gg_ * 16 + l15) ^ (4 + q4)) * 8;   \
            short8 vf1_ = *(short8*)&VtL[cur][vo2_];                         \
            o_[gg_] = MFMA16(pf1_, vf1_, o_[gg_]);                           \
        }                                                                    \
        __builtin_amdgcn_s_setprio(0);                                       \
    }

#define WRITE_CTX(qb_, o_, lsc_)                                             \
    {                                                                        \
        float ls0_ = __shfl(lsc_, q4 * 4 + 0, 64);                           \
        float ls1_ = __shfl(lsc_, q4 * 4 + 1, 64);                           \
        float ls2_ = __shfl(lsc_, q4 * 4 + 2, 64);                           \
        float ls3_ = __shfl(lsc_, q4 * 4 + 3, 64);                           \
        float lsr_[4] = {ls0_, ls1_, ls2_, ls3_};                            \
        _Pragma("unroll") for (int gg_ = 0; gg_ < 4; gg_++)                  \
            _Pragma("unroll") for (int r_ = 0; r_ < 4; r_++) {               \
                int q_ = (qb_) + wav * 16 + q4 * 4 + r_;                     \
                int mrow_ = b * SS + q_;                                     \
                int k_ = h * 64 + gg_ * 16 + l15;                            \
                HiLo hl_ = split2(o_[gg_][r_] / lsr_[r_]);                   \
                size_t off_ = ((size_t)(mrow_ >> 7) * 32 + (k_ >> 5)) * 4096 \
                    + (size_t)((k_ >> 3) & 3) * 1024 + (mrow_ & 127) * 8 + (k_ & 7); \
                ctxhi[off_] = hl_.hi;                                        \
                ctxlo[off_] = hl_.lo;                                        \
            }                                                                \
    }

    int x = blockIdx.x;
    int qtA = 31 - x, qtB = x;
    int qbA = qtA * 64, qbB = qtB * 64;

    short8 qA0h, qA0l, qA1h, qA1l, qB0h, qB0l, qB1h, qB1l;
    LOADQ(qbA, qA0h, qA0l, qA1h, qA1l);
    LOADQ(qbB, qB0h, qB0l, qB1h, qB1l);

    f32x4 oA[4] = {}, oB[4] = {};
    float mscA = -1e30f, lscA = 0.f, mscB = -1e30f, lscB = 0.f;
    int nch = qtA + 1;

    ISSUE(0, 0);
    __syncthreads();    // implicit vmcnt(0): chunk 0 staged

    for (int c = 0; c < nch; ++c) {
        int cur = c & 1;
        int k0 = c * 64;

        if (c + 1 < nch) ISSUE(c + 1, cur ^ 1);

        TILE_STEP(qtA, qbA, qA0h, qA0l, qA1h, qA1l, oA, mscA, lscA);
        if (c <= qtB)
            TILE_STEP(qtB, qbB, qB0h, qB0l, qB1h, qB1l, oB, mscB, lscB);

        __syncthreads();   // drains next-chunk gl_lds; orders buffer reuse
    }

    WRITE_CTX(qbA, oA, lscA);
    WRITE_CTX(qbB, oB, lscB);
#undef ISSUE
#undef LOADQ
#undef TILE_STEP
#undef WRITE_CTX
}

extern "C" void kernel_launch(void* const* d_in, const int* in_sizes, int n_in,
                              void* d_out, int out_size, void* d_ws, size_t ws_size,
                              hipStream_t stream) {
    const float* x  = (const float*)d_in[0];
    const float* Wq = (const float*)d_in[1];
    const float* bq = (const float*)d_in[2];
    const float* Al = (const float*)d_in[3];
    const float* Bl = (const float*)d_in[4];
    const float* Wp = (const float*)d_in[5];
    const float* bp = (const float*)d_in[6];

    char* ws = (char*)d_ws;
    float* qf     = (float*)(ws);                             // 0-16 MB
    short* khi    = (short*)(ws + (size_t)16 * 1024 * 1024);  // 16-24
    short* klo    = (short*)(ws + (size_t)24 * 1024 * 1024);  // 24-32
    short* vt     = (short*)(ws + (size_t)32 * 1024 * 1024);  // 32-40
    short* wpt_hi = (short*)(ws + (size_t)40 * 1024 * 1024);  // 40-42
    short* wpt_lo = (short*)(ws + (size_t)42 * 1024 * 1024);  // 42-44
    short* wqt_hi = (short*)(ws + (size_t)44 * 1024 * 1024);  // 44-50
    short* wqt_lo = (short*)(ws + (size_t)50 * 1024 * 1024);  // 50-56
    short* xhi    = (short*)(ws + (size_t)56 * 1024 * 1024);  // 56-64
    short* xlo    = (short*)(ws + (size_t)64 * 1024 * 1024);  // 64-72
    short* ctxhi  = (short*)(ws + (size_t)44 * 1024 * 1024);  // 44-52 (overlays dead wqt_hi)
    short* ctxlo  = (short*)(ws + (size_t)52 * 1024 * 1024);  // 52-60 (overlays dead wqt_lo/xhi)

    hipLaunchKernelGGL(prep_all, dim3(2048), dim3(256), 0, stream,
                       x, xhi, xlo, Wq, Al, Bl, wqt_hi, wqt_lo,
                       Wp, wpt_hi, wpt_lo);
    hipLaunchKernelGGL(gemm3, dim3(N3 / 128, MR / 128), dim3(256), 0, stream,
                       xhi, xlo, wqt_hi, wqt_lo, bq,
                       qf, khi, klo, vt, (float*)nullptr, N3, 0);
    hipLaunchKernelGGL(attn_mfma, dim3(SS / 128, HH, BB), dim3(256), 0, stream,
                       qf, khi, klo, vt, ctxhi, ctxlo);
    hipLaunchKernelGGL(gemm_proj, dim3(DD / 64, MR / 128), dim3(256), 0, stream,
                       ctxhi, ctxlo, wpt_hi, wpt_lo, bp, (float*)d_out);
}